// Round 12
// baseline (71.427 us; speedup 1.0000x reference)
//
#include <hip/hip_runtime.h>
#include <hip/hip_bf16.h>
#include <math.h>

#define N_NODES 204800
#define B_GRAPHS 4096
#define DIM 128

typedef __attribute__((ext_vector_type(8))) short bf16x8;
typedef __attribute__((ext_vector_type(4))) float f32x4;

__device__ __forceinline__ float sigf(float x) {
    return 1.0f / (1.0f + __expf(-x));
}

// round-to-nearest-even fp32 -> bf16
__device__ __forceinline__ unsigned short bfrne(float x) {
    unsigned u = __float_as_uint(x);
    unsigned r = u + 0x7FFFu + ((u >> 16) & 1u);
    return (unsigned short)(r >> 16);
}

// ---------------------------------------------------------------------------
// Kernel 1, three independent jobs selected by blockIdx.x:
//   [0..512):    q[b] = U_feat[b]@W_user + b_user + feat[last[b]]@W_last
//   [512..576):  Wf fragment table: Wf[((c*4+ks)*64+l)*8+j] =
//                bf16(W_key[(ks*32+(l>>4)*8+j)*128 + (c*16+(l&15))])
//                -> ekernel's per-(c,ks) wave read is lane-linear, 0 conflicts
//   [576..2176): segment bounds scatter: bounds[b] = first node of graph b
// ---------------------------------------------------------------------------
__global__ __launch_bounds__(128) void qkernel(
    const float* __restrict__ feat, const float* __restrict__ U_feat,
    const float* __restrict__ W_user, const float* __restrict__ b_user,
    const float* __restrict__ W_last, const int* __restrict__ last_nodes,
    const float* __restrict__ W_key, unsigned short* __restrict__ Wf,
    const int* __restrict__ seg, int* __restrict__ bounds,
    float* __restrict__ q) {
  if (blockIdx.x >= 576) {
    int n = (blockIdx.x - 576) * 128 + threadIdx.x;
    int sc = seg[n];
    int sp = (n == 0) ? -1 : seg[n - 1];
    for (int b = sp + 1; b <= sc; ++b) bounds[b] = (b == 0) ? 0 : n;
    if (n == N_NODES - 1)
      for (int b = sc + 1; b <= B_GRAPHS; ++b) bounds[b] = N_NODES;
    return;
  }
  if (blockIdx.x >= 512) {
    int b = blockIdx.x - 512;  // 0..63
#pragma unroll
    for (int jj = 0; jj < 2; ++jj) {
      int o = b * 256 + jj * 128 + threadIdx.x;  // halfword index in Wf
      int j = o & 7;
      int l = (o >> 3) & 63;
      int ks = (o >> 9) & 3;
      int c = o >> 11;
      int k = ks * 32 + (l >> 4) * 8 + j;
      int row = c * 16 + (l & 15);
      Wf[o] = bfrne(W_key[k * DIM + row]);
    }
    return;
  }
  __shared__ float sU[8][DIM];
  __shared__ float sL[8][DIM];
  const int d = threadIdx.x;
  const int g0 = blockIdx.x * 8;
  for (int g = 0; g < 8; ++g) {
    sU[g][d] = U_feat[(g0 + g) * DIM + d];
    int ln = last_nodes[g0 + g];
    sL[g][d] = feat[ln * DIM + d];
  }
  __syncthreads();
  float acc[8];
#pragma unroll
  for (int g = 0; g < 8; ++g) acc[g] = 0.0f;

  for (int kk = 0; kk < 32; ++kk) {
    float wu[4], wl[4];
#pragma unroll
    for (int j = 0; j < 4; ++j) {
      wu[j] = W_user[(kk * 4 + j) * DIM + d];
      wl[j] = W_last[(kk * 4 + j) * DIM + d];
    }
#pragma unroll
    for (int g = 0; g < 8; ++g) {
      float4 u4 = reinterpret_cast<const float4*>(sU[g])[kk];
      float4 l4 = reinterpret_cast<const float4*>(sL[g])[kk];
      acc[g] += u4.x * wu[0] + u4.y * wu[1] + u4.z * wu[2] + u4.w * wu[3];
      acc[g] += l4.x * wl[0] + l4.y * wl[1] + l4.z * wl[2] + l4.w * wl[3];
    }
  }
  float bu = b_user[d];
  for (int g = 0; g < 8; ++g) q[(g0 + g) * DIM + d] = acc[g] + bu;
}

// ---------------------------------------------------------------------------
// Kernel 2: e[n] = sigmoid(q[seg[n]] + (feat[n] @ W_key)) . w_e + log(cnt[n])
// Persistent pipelined version. 800 blocks x 256 thr (4 waves); each wave
// owns 4 16-node tiles (block covers 256 nodes). Wf staged ONCE (lane-linear
// fragment table -> conflict-free ds_read_b128, no XOR math), one barrier
// total; the t-loop is barrier-free and prefetches tile t+1's seg/cnt/feat
// during tile t's c-loop, so the wave issues loads continuously.
// Swapped-operand MFMA: D[keycol = c*16 + 4*lh + r][node = lr].
// ---------------------------------------------------------------------------
__global__ __launch_bounds__(256, 4) void ekernel(
    const float* __restrict__ feat, const unsigned short* __restrict__ Wf,
    const float* __restrict__ w_e, const float* __restrict__ cnt,
    const int* __restrict__ seg, const float* __restrict__ q,
    float* __restrict__ e) {
  __shared__ unsigned short sWf[128 * DIM];  // 32 KB fragment-ordered
  __shared__ float sWe[DIM];
  const int tid = threadIdx.x;
  const int base = blockIdx.x * 256;
  const int l = tid & 63, w = tid >> 6;  // 4 waves
  const int lr = l & 15, lh = l >> 4;

  // ---- stage Wf (linear copy: 2048 uint4 / 256 thr = 8 each) + w_e
  const uint4* Wf4 = reinterpret_cast<const uint4*>(Wf);
  uint4* sWf4 = reinterpret_cast<uint4*>(sWf);
#pragma unroll
  for (int i = 0; i < 8; ++i) sWf4[i * 256 + tid] = Wf4[i * 256 + tid];
  if (tid < 32)
    reinterpret_cast<float4*>(sWe)[tid] =
        reinterpret_cast<const float4*>(w_e)[tid];

  // ---- prologue: tile 0 scalars + feat burst
  int node = base + w * 16 + lr;
  int sg = seg[node];
  float lc = cnt[node];
  float4 fv[4][2];
  {
    const float* rp = feat + (size_t)node * DIM + lh * 8;
#pragma unroll
    for (int ks = 0; ks < 4; ++ks) {
      fv[ks][0] = *reinterpret_cast<const float4*>(rp + ks * 32);
      fv[ks][1] = *reinterpret_cast<const float4*>(rp + ks * 32 + 4);
    }
  }

  __syncthreads();  // Wf ready (the only barrier)

  const float4* q4p = reinterpret_cast<const float4*>(q);
  const bf16x8* sWfb = reinterpret_cast<const bf16x8*>(sWf);

#pragma unroll
  for (int t = 0; t < 4; ++t) {
    // ---- prefetch next tile's scalars (seg chain starts early)
    int nodeN = 0, sgN = 0;
    float lcN = 0.0f;
    if (t < 3) {
      nodeN = base + ((t + 1) * 4 + w) * 16 + lr;
      sgN = seg[nodeN];
      lcN = cnt[nodeN];
    }

    // ---- q gather first half for current tile
    float4 qvA[4];
#pragma unroll
    for (int c = 0; c < 4; ++c) qvA[c] = q4p[(size_t)sg * 32 + c * 4 + lh];

    // ---- cvt current feat to fragments (frees fv)
    bf16x8 af[4];
#pragma unroll
    for (int ks = 0; ks < 4; ++ks) {
      union { bf16x8 v; unsigned short u[8]; } a;
      a.u[0] = bfrne(fv[ks][0].x); a.u[1] = bfrne(fv[ks][0].y);
      a.u[2] = bfrne(fv[ks][0].z); a.u[3] = bfrne(fv[ks][0].w);
      a.u[4] = bfrne(fv[ks][1].x); a.u[5] = bfrne(fv[ks][1].y);
      a.u[6] = bfrne(fv[ks][1].z); a.u[7] = bfrne(fv[ks][1].w);
      af[ks] = a.v;
    }

    // ---- issue next tile's feat burst (latency hides under c-loop)
    if (t < 3) {
      const float* rp = feat + (size_t)nodeN * DIM + lh * 8;
#pragma unroll
      for (int ks = 0; ks < 4; ++ks) {
        fv[ks][0] = *reinterpret_cast<const float4*>(rp + ks * 32);
        fv[ks][1] = *reinterpret_cast<const float4*>(rp + ks * 32 + 4);
      }
    }

    // ---- q gather second half (in flight during c = 0..3)
    float4 qvB[4];
#pragma unroll
    for (int c = 0; c < 4; ++c)
      qvB[c] = q4p[(size_t)sg * 32 + 16 + c * 4 + lh];

    // ---- c-loop: 8 keycol-tiles; Wf reads are lane-linear (conflict-free)
    float p = 0.0f;
#pragma unroll
    for (int c = 0; c < 8; ++c) {
      bf16x8 wf[4];
#pragma unroll
      for (int ks = 0; ks < 4; ++ks) wf[ks] = sWfb[(c * 4 + ks) * 64 + l];

      f32x4 a0 = f32x4{0.f, 0.f, 0.f, 0.f};
#pragma unroll
      for (int ks = 0; ks < 4; ++ks)
        a0 = __builtin_amdgcn_mfma_f32_16x16x32_bf16(wf[ks], af[ks], a0, 0, 0, 0);

      float4 we = *reinterpret_cast<const float4*>(&sWe[c * 16 + lh * 4]);
      float4 qc = (c < 4) ? qvA[c & 3] : qvB[c & 3];
      p += we.x * sigf(a0[0] + qc.x) + we.y * sigf(a0[1] + qc.y) +
           we.z * sigf(a0[2] + qc.z) + we.w * sigf(a0[3] + qc.w);
    }

    // ---- reduce over lh, write e
    p += __shfl_xor(p, 16, 64);
    p += __shfl_xor(p, 32, 64);
    if (lh == 0) e[node] = p + __logf(lc);

    // ---- rotate pipeline registers
    node = nodeN; sg = sgN; lc = lcN;
  }
}

// ---------------------------------------------------------------------------
// Kernel 3: wave-per-graph segment softmax + weighted feat sum (no max pass;
// e bounded: |sig-sum| <= ~9, log(cnt) <= 3.9 -> exp(e) <= ~5.4e5, fp32-safe).
// ---------------------------------------------------------------------------
__global__ __launch_bounds__(256) void skernel(
    const float* __restrict__ feat, const int* __restrict__ bounds,
    const float* __restrict__ e, float* __restrict__ rst) {
  const int wave = threadIdx.x >> 6;
  const int lane = threadIdx.x & 63;
  const int g = blockIdx.x * 4 + wave;
  const int s0 = bounds[g], s1 = bounds[g + 1];

  if (s1 <= s0) {
    if (lane < 32)
      reinterpret_cast<float4*>(rst)[(size_t)g * 32 + lane] =
          float4{0.f, 0.f, 0.f, 0.f};
    return;
  }

  float ls = 0.0f;
  for (int i = s0 + lane; i < s1; i += 64) ls += __expf(e[i]);
#pragma unroll
  for (int off = 32; off >= 1; off >>= 1) ls += __shfl_xor(ls, off, 64);
  const float inv = 1.0f / ls;

  const int c = lane & 31;
  const int h = lane >> 5;
  float4 acc = float4{0.f, 0.f, 0.f, 0.f};
  const float4* feat4 = reinterpret_cast<const float4*>(feat);
  for (int n = s0 + h; n < s1; n += 2) {
    float pp = __expf(e[n]);
    float4 f = feat4[(size_t)n * 32 + c];
    acc.x += pp * f.x;
    acc.y += pp * f.y;
    acc.z += pp * f.z;
    acc.w += pp * f.w;
  }
  acc.x += __shfl_xor(acc.x, 32, 64);
  acc.y += __shfl_xor(acc.y, 32, 64);
  acc.z += __shfl_xor(acc.z, 32, 64);
  acc.w += __shfl_xor(acc.w, 32, 64);
  if (h == 0) {
    float4 r;
    r.x = acc.x * inv; r.y = acc.y * inv; r.z = acc.z * inv; r.w = acc.w * inv;
    reinterpret_cast<float4*>(rst)[(size_t)g * 32 + c] = r;
  }
}

// ---------------------------------------------------------------------------
extern "C" void kernel_launch(void* const* d_in, const int* in_sizes, int n_in,
                              void* d_out, int out_size, void* d_ws,
                              size_t ws_size, hipStream_t stream) {
  const float* feat = (const float*)d_in[0];
  const float* U_feat = (const float*)d_in[1];
  const float* cnt = (const float*)d_in[2];
  const float* W_key = (const float*)d_in[3];
  const float* W_user = (const float*)d_in[4];
  const float* b_user = (const float*)d_in[5];
  const float* W_last = (const float*)d_in[6];
  const float* w_e = (const float*)d_in[7];
  const int* last_nodes = (const int*)d_in[8];
  const int* seg = (const int*)d_in[9];
  float* out = (float*)d_out;

  float* q = (float*)d_ws;                       // 4096*128 f32 (2 MB)
  float* e = q + B_GRAPHS * DIM;                 // 204800 f32 (0.82 MB)
  unsigned short* Wf = (unsigned short*)(e + N_NODES);   // 16384 bf16 (32 KB)
  int* bounds = (int*)(Wf + DIM * DIM);          // 4097 ints

  qkernel<<<512 + 64 + N_NODES / 128, 128, 0, stream>>>(
      feat, U_feat, W_user, b_user, W_last, last_nodes, W_key, Wf, seg, bounds, q);
  ekernel<<<N_NODES / 256, 256, 0, stream>>>(feat, Wf, w_e, cnt, seg, q, e);
  skernel<<<B_GRAPHS / 4, 256, 0, stream>>>(feat, bounds, e, out);
}